// Round 2
// baseline (90.371 us; speedup 1.0000x reference)
//
#include <hip/hip_runtime.h>
#include <stdint.h>

// UnfoldConv1d: y[b,o,t] = bias[o] + sum_j sum_c W[o, j*512+c] * x[b,c,t-2+j]
// B=8, C=512, T=4096, OUT=512, K=3.
// bf16 MFMA GEMM, M=OUT (A=W), N=t (B=xp), K=1536 flattened (j = kb>>3 is a
// row-shift on the xp side). 256x256 tile, BK=64, 8 waves (2Mx4N), 8-phase
// schedule with counted vmcnt(6) (T3+T4), setprio (T5), chunk-XOR LDS swizzle
// (T2), global_load_lds width-16 staging.

typedef float    f32x4  __attribute__((ext_vector_type(4)));
typedef short    bf16x8 __attribute__((ext_vector_type(8)));

#define C_DIM   512
#define T_DIM   4096
#define TP_DIM  4104
#define OUT_DIM 512
#define KF_DIM  1536
#define B_DIM   8

__device__ __forceinline__ uint16_t f2bf(float f) {
  union { float f; uint32_t u; } v; v.f = f;
  uint32_t u = v.u;
  return (uint16_t)((u + 0x7fffu + ((u >> 16) & 1u)) >> 16);  // RNE
}

__device__ __forceinline__ void gload_lds16(const uint16_t* g, uint16_t* l) {
  __builtin_amdgcn_global_load_lds(
      (const __attribute__((address_space(1))) uint32_t*)g,
      (__attribute__((address_space(3))) uint32_t*)l, 16, 0, 0);
}

// Stage one 64-row slab (64 rows x 64 cols bf16 = 8KB) = 1 gload_lds/thread.
// LDS dest linear; global source chunk pre-swizzled with ch ^= (row&7).
__device__ __forceinline__ void stage_slab(const uint16_t* __restrict__ srcbase,
                                           int stride, uint16_t* lds, int r0,
                                           int tid) {
  int row = r0 + (tid >> 3);
  int ch = tid & 7;
  const uint16_t* src = srcbase + (long)row * stride + ((ch ^ (row & 7)) << 3);
  gload_lds16(src, lds + (((r0 << 3) + ((tid >> 6) << 6)) << 3));
}

#define PH_MID() do { __builtin_amdgcn_s_barrier(); \
  asm volatile("s_waitcnt lgkmcnt(0)" ::: "memory"); \
  __builtin_amdgcn_sched_barrier(0); \
  __builtin_amdgcn_s_setprio(1); } while (0)

#define PH_END() do { __builtin_amdgcn_s_setprio(0); \
  __builtin_amdgcn_s_barrier(); } while (0)

#define READ_A(BUF, MH) do { \
  _Pragma("unroll") for (int mi = 0; mi < 4; ++mi) { \
    int row = wm * 128 + (MH) * 64 + mi * 16 + lr; \
    _Pragma("unroll") for (int kk = 0; kk < 2; ++kk) \
      af[mi][kk] = *(const bf16x8*)&(BUF)[row * 64 + (((kk * 4 + g) ^ (row & 7)) << 3)]; \
  } } while (0)

#define READ_B(BUF, NH) do { \
  _Pragma("unroll") for (int ni = 0; ni < 2; ++ni) { \
    int row = wn * 64 + (NH) * 32 + ni * 16 + lr; \
    _Pragma("unroll") for (int kk = 0; kk < 2; ++kk) \
      bfr[NH][ni][kk] = *(const bf16x8*)&(BUF)[row * 64 + (((kk * 4 + g) ^ (row & 7)) << 3)]; \
  } } while (0)

#define QUAD(MH, NH) do { \
  _Pragma("unroll") for (int mi = 0; mi < 4; ++mi) \
  _Pragma("unroll") for (int ni = 0; ni < 2; ++ni) \
  _Pragma("unroll") for (int kk = 0; kk < 2; ++kk) \
    acc[(MH) * 4 + mi][(NH) * 2 + ni] = __builtin_amdgcn_mfma_f32_16x16x32_bf16( \
        af[mi][kk], bfr[NH][ni][kk], acc[(MH) * 4 + mi][(NH) * 2 + ni], 0, 0, 0); \
  } while (0)

// One iteration = 2 K-tiles (kb0 even -> buf0, kb0+1 -> buf1), 8 phases.
// FULL=false: drain iteration (only ph1's stage of tile kb0+1 A slabs 1,3).
template<bool FULL>
__device__ __forceinline__ void iter8(
    f32x4 (&acc)[8][4],
    uint16_t* LA0, uint16_t* LB0, uint16_t* LA1, uint16_t* LB1,
    const uint16_t* __restrict__ wsrc,   // Wb + o0*KF
    const uint16_t* __restrict__ xsrc,   // xp + (b*TP + t0)*C
    int kb0, int tid, int wm, int wn, int lr, int g) {
  const uint16_t* a1 = wsrc + (kb0 + 1) * 64;
  const uint16_t* a2 = wsrc + (kb0 + 2) * 64;
  const uint16_t* a3 = wsrc + (kb0 + 3) * 64;
  const uint16_t* b2 = xsrc + ((kb0 + 2) >> 3) * C_DIM + (((kb0 + 2) & 7) << 6);
  const uint16_t* b3 = xsrc + ((kb0 + 3) >> 3) * C_DIM + (((kb0 + 3) & 7) << 6);

  bf16x8 af[4][2];
  bf16x8 bfr[2][2][2];

  // ph1: tile kb0 quadrant (mh0,nh0); stage buf1 A slabs 1,3 (tile kb0+1)
  READ_A(LA0, 0); READ_B(LB0, 0);
  stage_slab(a1, KF_DIM, LA1, 64, tid); stage_slab(a1, KF_DIM, LA1, 192, tid);
  PH_MID(); QUAD(0, 0); PH_END();
  // ph2: (mh0,nh1); stage buf0 A slabs 0,2 (tile kb0+2)
  READ_B(LB0, 1);
  if (FULL) { stage_slab(a2, KF_DIM, LA0, 0, tid); stage_slab(a2, KF_DIM, LA0, 128, tid); }
  PH_MID(); QUAD(0, 1); PH_END();
  // ph3: (mh1,nh1); stage buf0 B slabs 0,1
  READ_A(LA0, 1);
  if (FULL) { stage_slab(b2, C_DIM, LB0, 0, tid); stage_slab(b2, C_DIM, LB0, 64, tid); }
  PH_MID(); QUAD(1, 1); PH_END();
  // ph4: (mh1,nh0); stage buf0 B slabs 2,3; counted vmcnt
  if (FULL) { stage_slab(b2, C_DIM, LB0, 128, tid); stage_slab(b2, C_DIM, LB0, 192, tid); }
  PH_MID(); QUAD(1, 0);
  __builtin_amdgcn_s_setprio(0);
  if (FULL) asm volatile("s_waitcnt vmcnt(6)" ::: "memory");
  else      asm volatile("s_waitcnt vmcnt(0)" ::: "memory");
  __builtin_amdgcn_s_barrier();
  // ph5: tile kb0+1 (mh0,nh0); stage buf0 A slabs 1,3 (tile kb0+2)
  READ_A(LA1, 0); READ_B(LB1, 0);
  if (FULL) { stage_slab(a2, KF_DIM, LA0, 64, tid); stage_slab(a2, KF_DIM, LA0, 192, tid); }
  PH_MID(); QUAD(0, 0); PH_END();
  // ph6: (mh0,nh1); stage buf1 A slabs 0,2 (tile kb0+3)
  READ_B(LB1, 1);
  if (FULL) { stage_slab(a3, KF_DIM, LA1, 0, tid); stage_slab(a3, KF_DIM, LA1, 128, tid); }
  PH_MID(); QUAD(0, 1); PH_END();
  // ph7: (mh1,nh1); stage buf1 B slabs 0,1
  READ_A(LA1, 1);
  if (FULL) { stage_slab(b3, C_DIM, LB1, 0, tid); stage_slab(b3, C_DIM, LB1, 64, tid); }
  PH_MID(); QUAD(1, 1); PH_END();
  // ph8: (mh1,nh0); stage buf1 B slabs 2,3; counted vmcnt
  if (FULL) { stage_slab(b3, C_DIM, LB1, 128, tid); stage_slab(b3, C_DIM, LB1, 192, tid); }
  PH_MID(); QUAD(1, 0);
  __builtin_amdgcn_s_setprio(0);
  if (FULL) asm volatile("s_waitcnt vmcnt(6)" ::: "memory");
  __builtin_amdgcn_s_barrier();
}

// ---------------------------- main GEMM kernel -------------------------------
// grid (T/256=16, OUT/256=2, B=8), 512 threads = 8 waves (2M x 4N).
__global__ __launch_bounds__(512, 2) void gemm_kernel(
    const uint16_t* __restrict__ xp, const uint16_t* __restrict__ Wb,
    const float* __restrict__ bias, float* __restrict__ out) {
  __shared__ __align__(16) uint16_t LA0[256 * 64];
  __shared__ __align__(16) uint16_t LB0[256 * 64];
  __shared__ __align__(16) uint16_t LA1[256 * 64];
  __shared__ __align__(16) uint16_t LB1[256 * 64];

  const int tid  = threadIdx.x;
  const int lane = tid & 63;
  const int wid  = tid >> 6;
  const int wm   = wid >> 2;     // 0..1  (o / A side, 128 rows each)
  const int wn   = wid & 3;      // 0..3  (t / B side, 64 rows each)
  const int lr   = lane & 15;
  const int g    = lane >> 4;
  const int t0 = blockIdx.x * 256;
  const int o0 = blockIdx.y * 256;
  const int b  = blockIdx.z;

  const uint16_t* wsrc = Wb + (long)o0 * KF_DIM;
  const uint16_t* xsrc = xp + ((long)b * TP_DIM + t0) * C_DIM;

  f32x4 acc[8][4];
  #pragma unroll
  for (int mi = 0; mi < 8; ++mi)
    #pragma unroll
    for (int ni = 0; ni < 4; ++ni)
      #pragma unroll
      for (int r = 0; r < 4; ++r) acc[mi][ni][r] = 0.0f;

  // ---- prologue: tile0 full (buf0), tile1 A slabs {0,2} + B full (buf1) ----
  const uint16_t* a0 = wsrc;
  const uint16_t* a1 = wsrc + 64;
  const uint16_t* b0 = xsrc;          // kb=0: j=0, c0=0
  const uint16_t* b1 = xsrc + 64;     // kb=1: j=0, c0=64
  stage_slab(a0, KF_DIM, LA0, 0, tid);   stage_slab(a0, KF_DIM, LA0, 64, tid);
  stage_slab(a0, KF_DIM, LA0, 128, tid); stage_slab(a0, KF_DIM, LA0, 192, tid);
  stage_slab(b0, C_DIM, LB0, 0, tid);    stage_slab(b0, C_DIM, LB0, 64, tid);
  stage_slab(b0, C_DIM, LB0, 128, tid);  stage_slab(b0, C_DIM, LB0, 192, tid);
  stage_slab(a1, KF_DIM, LA1, 0, tid);   stage_slab(a1, KF_DIM, LA1, 128, tid);
  stage_slab(b1, C_DIM, LB1, 0, tid);    stage_slab(b1, C_DIM, LB1, 64, tid);
  stage_slab(b1, C_DIM, LB1, 128, tid);  stage_slab(b1, C_DIM, LB1, 192, tid);
  asm volatile("s_waitcnt vmcnt(6)" ::: "memory");  // tile0's 8 loads landed
  __builtin_amdgcn_s_barrier();

  // ---- main loop: 24 K-tiles = 11 full iterations + 1 drain ----
  #pragma unroll 1
  for (int i = 0; i < 11; ++i)
    iter8<true>(acc, LA0, LB0, LA1, LB1, wsrc, xsrc, 2 * i, tid, wm, wn, lr, g);
  iter8<false>(acc, LA0, LB0, LA1, LB1, wsrc, xsrc, 22, tid, wm, wn, lr, g);

  // ---- epilogue: D col=lane&15 (t), row=(lane>>4)*4+r (o) [m89-verified] ----
  #pragma unroll
  for (int mi = 0; mi < 8; ++mi) {
    int orow = o0 + wm * 128 + mi * 16 + (lane >> 4) * 4;
    #pragma unroll
    for (int ni = 0; ni < 4; ++ni) {
      int t = t0 + wn * 64 + ni * 16 + lr;
      float* op = out + ((long)b * OUT_DIM + orow) * T_DIM + t;
      #pragma unroll
      for (int r = 0; r < 4; ++r)
        op[(long)r * T_DIM] = acc[mi][ni][r] + bias[orow + r];
    }
  }
}

// ---------------- prep: W fp32 [512][1536] -> bf16 same layout ----------------
__global__ __launch_bounds__(256) void prep_w(const float* __restrict__ W,
                                              uint16_t* __restrict__ Wb) {
  int i = blockIdx.x * 256 + threadIdx.x;  // float4 units: 786432/4 = 196608
  if (i >= 196608) return;
  float4 v = ((const float4*)W)[i];
  ushort4 o;
  o.x = f2bf(v.x); o.y = f2bf(v.y); o.z = f2bf(v.z); o.w = f2bf(v.w);
  ((ushort4*)Wb)[i] = o;
}

// ------ prep: x fp32 [b][c][t] -> xp bf16 [b][tp][c], tp=t+2, TP=4104 --------
__global__ __launch_bounds__(256) void prep_x(const float* __restrict__ x,
                                              uint16_t* __restrict__ xp) {
  __shared__ uint16_t tile[64 * 66];
  const int tid = threadIdx.x;
  const int tp0 = blockIdx.x * 64;
  const int c0  = blockIdx.y * 64;
  const int b   = blockIdx.z;
  #pragma unroll
  for (int it = 0; it < 8; ++it) {
    int u = it * 256 + tid;
    int crow = u >> 5;
    int p = u & 31;
    int t = tp0 - 2 + p * 2;
    float vx = 0.f, vy = 0.f;
    if (t >= 0 && t < T_DIM) {
      const float2 v = *(const float2*)(x + (long)(b * C_DIM + c0 + crow) * T_DIM + t);
      vx = v.x; vy = v.y;
    }
    tile[(2 * p) * 66 + crow]     = f2bf(vx);
    tile[(2 * p + 1) * 66 + crow] = f2bf(vy);
  }
  __syncthreads();
  #pragma unroll
  for (int it = 0; it < 8; ++it) {
    int u = it * 256 + tid;
    int tl = u >> 5;
    int q = u & 31;
    int tp = tp0 + tl;
    if (tp < TP_DIM) {
      ushort2 val;
      val.x = tile[tl * 66 + 2 * q];
      val.y = tile[tl * 66 + 2 * q + 1];
      *(ushort2*)(xp + (long)(b * TP_DIM + tp) * C_DIM + c0 + 2 * q) = val;
    }
  }
}

// ------------------------- naive fallback (no ws) ----------------------------
__global__ __launch_bounds__(256) void naive_kernel(const float* __restrict__ x,
                                                    const float* __restrict__ W,
                                                    const float* __restrict__ bias,
                                                    float* __restrict__ y) {
  int t = blockIdx.x * 256 + threadIdx.x;
  int o = blockIdx.y, b = blockIdx.z;
  float s = bias[o];
  #pragma unroll
  for (int j = 0; j < 3; ++j) {
    int tt = t - 2 + j;
    if (tt < 0) continue;
    const float* xr = x + (long)b * C_DIM * T_DIM + tt;
    const float* wr = W + (long)o * KF_DIM + j * C_DIM;
    float a = 0.f;
    for (int c = 0; c < C_DIM; ++c) a += wr[c] * xr[(long)c * T_DIM];
    s += a;
  }
  y[((long)b * OUT_DIM + o) * T_DIM + t] = s;
}

extern "C" void kernel_launch(void* const* d_in, const int* in_sizes, int n_in,
                              void* d_out, int out_size, void* d_ws, size_t ws_size,
                              hipStream_t stream) {
  (void)in_sizes; (void)n_in; (void)out_size;
  const float* x    = (const float*)d_in[0];
  const float* W    = (const float*)d_in[1];
  const float* bias = (const float*)d_in[2];
  float* out = (float*)d_out;

  const size_t wb_elems = (size_t)OUT_DIM * KF_DIM;          // 786432
  const size_t xp_elems = (size_t)B_DIM * TP_DIM * C_DIM;    // 16809984
  const size_t need = (wb_elems + xp_elems) * sizeof(uint16_t);

  if (ws_size < need) {  // insurance: slow but correct
    naive_kernel<<<dim3(T_DIM / 256, OUT_DIM, B_DIM), 256, 0, stream>>>(x, W, bias, out);
    return;
  }

  uint16_t* Wb = (uint16_t*)d_ws;
  uint16_t* xp = (uint16_t*)d_ws + wb_elems;

  prep_w<<<768, 256, 0, stream>>>(W, Wb);
  prep_x<<<dim3(65, 8, 8), 256, 0, stream>>>(x, xp);
  gemm_kernel<<<dim3(16, 2, 8), 512, 0, stream>>>(xp, Wb, bias, out);
}